// Round 4
// baseline (249.487 us; speedup 1.0000x reference)
//
#include <hip/hip_runtime.h>

// QLinear: y[n,o] = round((sum_k (x[n,k]-xz)*(w[o,k]-wz) + bias[o]) * M + yz)
// N=65536, K=512, OUT=512.
// Exact i8 path: (x-128),(w-128) in [-128,127]; |dot+bias| < 2^24; f32 epilogue exact.
// Barrier-free design: A-fragments built per-lane in registers (lane owns row fr,
// k-chunk fq*16 -- exactly the mfma_i32_16x16x64_i8 A layout). B (256 KB) lives
// in 64 VGPRs per wave for its 32 output cols x full K. No LDS at all.

#define K_DIM 512
#define OUTF  512

typedef __attribute__((ext_vector_type(4))) int   i32x4;
typedef __attribute__((ext_vector_type(4))) float f32x4;

// ---------- prepass: weight int32 -> i8 (w - wz), row-major [o][k] ----------
__global__ void wprep(const int* __restrict__ W, unsigned int* __restrict__ Wb,
                      const float* __restrict__ wzp) {
    const int wz = __float2int_rn(wzp[0]);
    int idx = (blockIdx.x * blockDim.x + threadIdx.x) * 4;
    i32x4 w = *reinterpret_cast<const i32x4*>(W + idx);
    unsigned int p = ((unsigned int)(w[0] - wz) & 0xffu)
                   | (((unsigned int)(w[1] - wz) & 0xffu) << 8)
                   | (((unsigned int)(w[2] - wz) & 0xffu) << 16)
                   | (((unsigned int)(w[3] - wz) & 0xffu) << 24);
    Wb[idx >> 2] = p;
}

// ---------- main: barrier-free streaming GEMM ----------
// 1024 blocks x 256 thr (4 waves). Block-tile: 16 rows x 128 cols; wave owns 32 cols.
// Block processes 16 row-tiles (stride 256 tiles) with the same cols -> B loaded once.
__global__ __launch_bounds__(256, 4)
void qgemm(const float* __restrict__ X,
           const unsigned char* __restrict__ Wb,
           const int* __restrict__ bias,
           const float* __restrict__ Mp,
           const float* __restrict__ xzp,
           const float* __restrict__ yzp,
           float* __restrict__ Y) {
    const int tid  = threadIdx.x;
    const int lane = tid & 63;
    const int wid  = tid >> 6;            // 0..3
    const int fr   = lane & 15;
    const int fq   = lane >> 4;

    // XCD-aware decomposition: xcd = b&7; within XCD: col-tile fastest so the
    // 4 col-blocks sharing a row-panel co-reside on one XCD's L2.
    const int b    = blockIdx.x;          // [0,1024)
    const int q    = b >> 3;              // [0,128)
    const int c    = q & 3;               // col-tile (128 cols)
    const int rbase= (b & 7) * 32 + (q >> 2);   // [0,256); row-tiles rbase + 256*t

    const int c0 = c * 128 + wid * 32;    // wave's col base

    const float Mv  = Mp[0];
    const float xzf = xzp[0];
    const float yzf = yzp[0];

    // ---- B fragments: 2 col-frags x 8 k-steps, resident in registers ----
    i32x4 bf0[8], bf1[8];
    {
        const unsigned char* wb = Wb + (size_t)(c0 + fr) * K_DIM + fq * 16;
        #pragma unroll
        for (int ks = 0; ks < 8; ++ks) {
            bf0[ks] = *reinterpret_cast<const i32x4*>(wb + ks * 64);
            bf1[ks] = *reinterpret_cast<const i32x4*>(wb + 16 * K_DIM + ks * 64);
        }
    }

    // bias folded into accumulator init (col = c0 + n*16 + fr, same for all j)
    const int bv0 = bias[c0 + fr];
    const int bv1 = bias[c0 + 16 + fr];
    const i32x4 init0 = {bv0, bv0, bv0, bv0};
    const i32x4 init1 = {bv1, bv1, bv1, bv1};
    i32x4 acc0 = init0, acc1 = init1;

    // ---- A streaming: lane loads 16 consecutive f32 of row (row0t + fr) ----
    const size_t TILE_STRIDE = (size_t)256 * 16 * K_DIM;   // floats between row-tiles
    const float* ax = X + ((size_t)rbase * 16 + fr) * K_DIM + fq * 16;

    f32x4 bufA[4], bufB[4];

    auto loadA = [&](f32x4 (&dst)[4], const float* p) {
        #pragma unroll
        for (int qq = 0; qq < 4; ++qq)
            dst[qq] = *reinterpret_cast<const f32x4*>(p + qq * 4);
    };
    auto convA = [&](const f32x4 (&src)[4], i32x4& af) {
        #pragma unroll
        for (int qq = 0; qq < 4; ++qq) {
            unsigned int u0 = (unsigned int)(int)(src[qq][0] - xzf) & 0xffu;
            unsigned int u1 = (unsigned int)(int)(src[qq][1] - xzf) & 0xffu;
            unsigned int u2 = (unsigned int)(int)(src[qq][2] - xzf) & 0xffu;
            unsigned int u3 = (unsigned int)(int)(src[qq][3] - xzf) & 0xffu;
            af[qq] = (int)(u0 | (u1 << 8) | (u2 << 16) | (u3 << 24));
        }
    };

    loadA(bufA, ax);                      // prefetch (t=0, ks=0)

    for (int t = 0; t < 16; ++t) {
        const float* axn = ax + TILE_STRIDE;
        const float* pfTile = (t < 15) ? axn : ax;    // clamped redundant prefetch at end

        #pragma unroll
        for (int ks = 0; ks < 8; ++ks) {
            const float* pf = (ks < 7) ? (ax + (ks + 1) * 64) : pfTile;
            i32x4 af;
            if ((ks & 1) == 0) { loadA(bufB, pf); convA(bufA, af); }
            else               { loadA(bufA, pf); convA(bufB, af); }
            acc0 = __builtin_amdgcn_mfma_i32_16x16x64_i8(af, bf0[ks], acc0, 0, 0, 0);
            acc1 = __builtin_amdgcn_mfma_i32_16x16x64_i8(af, bf1[ks], acc1, 0, 0, 0);
        }

        // epilogue for this 16-row tile: y = rintf(acc * M + yz)   (bias pre-folded)
        const size_t row0t = ((size_t)rbase + (size_t)t * 256) * 16;
        float* yp = Y + (row0t + fq * 4) * OUTF + c0 + fr;
        #pragma unroll
        for (int j = 0; j < 4; ++j) {
            yp[(size_t)j * OUTF]      = rintf((float)acc0[j] * Mv + yzf);
            yp[(size_t)j * OUTF + 16] = rintf((float)acc1[j] * Mv + yzf);
        }
        acc0 = init0;
        acc1 = init1;
        ax = axn;
    }
}

extern "C" void kernel_launch(void* const* d_in, const int* in_sizes, int n_in,
                              void* d_out, int out_size, void* d_ws, size_t ws_size,
                              hipStream_t stream) {
    const float* x    = (const float*)d_in[0];
    const int*   w    = (const int*)d_in[1];
    const int*   bias = (const int*)d_in[2];
    const float* M    = (const float*)d_in[3];
    const float* xz   = (const float*)d_in[4];
    const float* wz   = (const float*)d_in[5];
    const float* yz   = (const float*)d_in[6];
    float* y = (float*)d_out;

    unsigned int* Wb = (unsigned int*)d_ws;     // 512*512 i8 = 256 KB

    wprep<<<256, 256, 0, stream>>>(w, Wb, wz);
    qgemm<<<1024, 256, 0, stream>>>(x, (const unsigned char*)Wb, bias, M, xz, yz, y);
}

// Round 5
// 68.669 us; speedup vs baseline: 3.6332x; 3.6332x over previous
//
#include <hip/hip_runtime.h>

// QLinear: y[n,o] = round((sum_k (x[n,k]-xz)*(w[o,k]-wz) + bias[o]) * M + yz)
// N=65536, K=512, OUT=512.
// Exact i8 path: (x-128),(w-128) in [-128,127]; |dot+bias| < 2^24; f32 epilogue exact.
// R5 = R2 structure + prefetch-distance-2 register staging (counted-vmcnt via
// register deps), bias folded into acc init, nontemporal y stores.

#define K_DIM 512
#define OUTF  512
#define NT    8            // K_DIM / 64
#define LDAB  80           // LDS row stride bytes: 64 data + 16 pad (<=2-way on b128)
#define TILE_B (128 * LDAB)
#define BUF_B  (2 * TILE_B)

typedef __attribute__((ext_vector_type(4))) int   i32x4;
typedef __attribute__((ext_vector_type(4))) float f32x4;

// ---------- prepass: weight int32 -> i8 (w - wz), row-major [o][k] ----------
__global__ void wprep(const int* __restrict__ W, unsigned int* __restrict__ Wb,
                      const float* __restrict__ wzp) {
    const int wz = __float2int_rn(wzp[0]);
    int idx = (blockIdx.x * blockDim.x + threadIdx.x) * 4;
    i32x4 w = *reinterpret_cast<const i32x4*>(W + idx);
    unsigned int p = ((unsigned int)(w[0] - wz) & 0xffu)
                   | (((unsigned int)(w[1] - wz) & 0xffu) << 8)
                   | (((unsigned int)(w[2] - wz) & 0xffu) << 16)
                   | (((unsigned int)(w[3] - wz) & 0xffu) << 24);
    Wb[idx >> 2] = p;
}

__global__ __launch_bounds__(512, 4)
void qgemm(const float* __restrict__ X,
           const unsigned char* __restrict__ Wb,
           const int* __restrict__ bias,
           const float* __restrict__ Mp,
           const float* __restrict__ xzp,
           const float* __restrict__ yzp,
           float* __restrict__ Y) {
    __shared__ unsigned char lds[2 * BUF_B];   // 40960 B

    const int tid  = threadIdx.x;
    const int lane = tid & 63;
    const int wid  = tid >> 6;                 // 0..7
    const int wr   = wid >> 2;                 // row 64-strip
    const int wc   = wid & 3;                  // col 32-strip
    const int fr   = lane & 15;
    const int fq   = lane >> 4;

    // XCD-contiguous bijective swizzle (2048 = 8 * 256); col-tile fastest
    const int b = blockIdx.x;
    const int lid = (b & 7) * 256 + (b >> 3);
    const int row0 = (lid >> 2) * 128;
    const int n0   = (lid & 3) * 128;

    const int xz = __float2int_rn(xzp[0]);

    // staging maps (512 threads):
    // A tile 128x64 f32: row = tid>>2, 16 f32 at col (tid&3)*16
    // B tile 128x64 i8 : row = tid>>2, 16 B   at col (tid&3)*16
    const int srow = tid >> 2;
    const int scol = (tid & 3) * 16;
    const float* xbase = X + (size_t)(row0 + srow) * K_DIM + scol;
    const unsigned char* wbase = Wb + (size_t)(n0 + srow) * K_DIM + scol;
    const int aoff = srow * LDAB + scol;
    const int boff = TILE_B + srow * LDAB + scol;

    f32x4 ra[2][4];        // two staging sets (prefetch distance 2)
    i32x4 rb[2];

    auto stage = [&](int t, int s) {
        const float* xp = xbase + t * 64;
        #pragma unroll
        for (int q = 0; q < 4; ++q)
            ra[s][q] = *reinterpret_cast<const f32x4*>(xp + q * 4);
        rb[s] = *reinterpret_cast<const i32x4*>(wbase + t * 64);
    };
    auto convwrite = [&](int buf, int s) {
        const int ab = buf * BUF_B;
        i32x4 pa;
        #pragma unroll
        for (int q = 0; q < 4; ++q) {
            unsigned int u0 = (unsigned int)((int)ra[s][q][0] - xz) & 0xffu;
            unsigned int u1 = (unsigned int)((int)ra[s][q][1] - xz) & 0xffu;
            unsigned int u2 = (unsigned int)((int)ra[s][q][2] - xz) & 0xffu;
            unsigned int u3 = (unsigned int)((int)ra[s][q][3] - xz) & 0xffu;
            pa[q] = (int)(u0 | (u1 << 8) | (u2 << 16) | (u3 << 24));
        }
        *reinterpret_cast<i32x4*>(&lds[ab + aoff]) = pa;
        *reinterpret_cast<i32x4*>(&lds[ab + boff]) = rb[s];
    };

    // bias folded into accumulator init
    const int c0 = n0 + wc * 32;
    const int bv0 = bias[c0 + fr];
    const int bv1 = bias[c0 + 16 + fr];
    i32x4 acc[4][2];
    #pragma unroll
    for (int m = 0; m < 4; ++m) {
        acc[m][0] = i32x4{bv0, bv0, bv0, bv0};
        acc[m][1] = i32x4{bv1, bv1, bv1, bv1};
    }

    const int aro = (wr * 64 + fr) * LDAB + fq * 16;
    const int bro = TILE_B + (wc * 32 + fr) * LDAB + fq * 16;

    auto compute = [&](int buf) {
        const int ab = buf * BUF_B;
        i32x4 af[4], bf[2];
        #pragma unroll
        for (int m = 0; m < 4; ++m)
            af[m] = *reinterpret_cast<const i32x4*>(&lds[ab + aro + m * 16 * LDAB]);
        #pragma unroll
        for (int n = 0; n < 2; ++n)
            bf[n] = *reinterpret_cast<const i32x4*>(&lds[ab + bro + n * 16 * LDAB]);
        #pragma unroll
        for (int m = 0; m < 4; ++m)
            #pragma unroll
            for (int n = 0; n < 2; ++n)
                acc[m][n] = __builtin_amdgcn_mfma_i32_16x16x64_i8(
                    af[m], bf[n], acc[m][n], 0, 0, 0);
    };

    // prologue: t=0 and t=1 loads in flight; write t=0 (waits only its own regs)
    stage(0, 0);
    stage(1, 1);
    convwrite(0, 0);
    __syncthreads();

    #pragma unroll
    for (int t = 0; t < NT; ++t) {
        if (t + 2 < NT) stage(t + 2, t & 1);          // issue far-ahead loads first
        compute(t & 1);
        if (t + 1 < NT) convwrite((t + 1) & 1, (t + 1) & 1);  // consume 1-iter-old loads
        __syncthreads();
    }

    // epilogue: y = rintf(acc * M + yz)   (bias pre-folded), nontemporal stores
    const float Mv = Mp[0], yz = yzp[0];
    #pragma unroll
    for (int n = 0; n < 2; ++n) {
        const int col = c0 + n * 16 + fr;
        #pragma unroll
        for (int m = 0; m < 4; ++m) {
            const int row = row0 + wr * 64 + m * 16 + fq * 4;
            float* yp = Y + (size_t)row * OUTF + col;
            #pragma unroll
            for (int j = 0; j < 4; ++j)
                __builtin_nontemporal_store(
                    rintf((float)acc[m][n][j] * Mv + yz), yp + (size_t)j * OUTF);
        }
    }
}

extern "C" void kernel_launch(void* const* d_in, const int* in_sizes, int n_in,
                              void* d_out, int out_size, void* d_ws, size_t ws_size,
                              hipStream_t stream) {
    const float* x    = (const float*)d_in[0];
    const int*   w    = (const int*)d_in[1];
    const int*   bias = (const int*)d_in[2];
    const float* M    = (const float*)d_in[3];
    const float* xz   = (const float*)d_in[4];
    const float* wz   = (const float*)d_in[5];
    const float* yz   = (const float*)d_in[6];
    float* y = (float*)d_out;

    unsigned int* Wb = (unsigned int*)d_ws;     // 512*512 i8 = 256 KB

    wprep<<<256, 256, 0, stream>>>(w, Wb, wz);
    qgemm<<<2048, 512, 0, stream>>>(x, (const unsigned char*)Wb, bias, M, xz, yz, y);
}